// Round 15
// baseline (991.797 us; speedup 1.0000x reference)
//
#include <hip/hip_runtime.h>

typedef _Float16 f16x8 __attribute__((ext_vector_type(8)));
typedef float f32x4 __attribute__((ext_vector_type(4)));

constexpr int D = 256;
constexpr int NUTT = 64;
constexpr int L = 512;
constexpr int G = 768;           // 3*D
constexpr int NBLK = 6;          // 128-col n-blocks over G=768
constexpr int NJOBS = 8 * NUTT * NBLK;     // 3072 producer jobs (64r x 128c)

// LDS-only barrier: orders ds_* ops across the workgroup WITHOUT draining
// vmcnt — global prefetch loads / wo16 stores stay in flight across steps.
__device__ __forceinline__ void lds_barrier() {
  asm volatile("s_waitcnt lgkmcnt(0)\n\ts_barrier" ::: "memory");
}

__device__ __forceinline__ float fast_rcp(float x) {
  return __builtin_amdgcn_rcpf(x);
}
__device__ __forceinline__ float sigm(float x) {
  return fast_rcp(1.0f + __expf(-x));
}
__device__ __forceinline__ float tanh_f(float x) {
  float ax = fabsf(x);
  float e = __expf(-2.0f * ax);
  float r = (1.0f - e) * fast_rcp(1.0f + e);
  return copysignf(r, x);
}

// chunk layout over the 8 rowblocks (64 steps each):
//   chunk 0 = rb0, chunk 1 = rb1, chunk 2 = rb2-3, chunk 3 = rb4-5,
//   chunk 4 = rb6-7.  Small early chunks cut the consumer lead-in.
__device__ __constant__ int c_chunk_of_rb[8] = {0, 1, 2, 2, 3, 3, 4, 4};

// ---------------------------------------------------------------------------
// Kernel A: pack Wih (f32) -> f16 hi/lo in MFMA fragment order (R9-verified,
// inverted map: thread = dst index, coalesced stores).
// Block 0 also zeroes the 512 producer-consumer flags (64B-padded).
// ---------------------------------------------------------------------------
__global__ __launch_bounds__(256) void pack_wih(
    const float* __restrict__ Wih, _Float16* __restrict__ hi,
    _Float16* __restrict__ lo, int* cnt) {
  if (blockIdx.x == 0) {
    cnt[threadIdx.x << 4] = 0;
    cnt[(threadIdx.x + 256) << 4] = 0;
  }
  const int d = blockIdx.x * 256 + threadIdx.x;    // grid = 768 blocks
  const int j = d & 7;
  const int l15 = (d >> 3) & 15;
  const int lk = (d >> 7) & 3;
  const int f = (d >> 9) & 7;
  const int it = d >> 12;
  const int g = 16 * it + l15;
  const int k = 32 * f + 8 * lk + j;
  float v = Wih[g * 256 + k];
  _Float16 h = (_Float16)v;
  hi[d] = h;
  lo[d] = (_Float16)(v - (float)h);
}

// ---------------------------------------------------------------------------
// Mega-kernel v15 = R14 (LDS-pad 1-block/CU exclusivity, verified 692) +
// (a) 2-STEP-DEEP gx prefetch: R12/R14 nulls (setprio, CU exclusivity)
//     localize the ~75 µs overlap penalty to memory-latency stalls during
//     the producer burst; doubling the prefetch budget to ~5400 cyc covers
//     contention-inflated HBM latency. Two rotating register triples.
// (b) 64-row transient producer jobs with chunks {64,64,128,128,128}
//     (R13's decomposition, now WITH the pad): chunk 0 = 384 half-size
//     jobs ≈ 2 rounds ≈ 12 µs lead-in (was ~25).
// Scan structure untouched (R6 proved restructuring regresses).
// ---------------------------------------------------------------------------
__global__ __launch_bounds__(512, 1) void hran_mega(
    const int* __restrict__ tokens, const float* __restrict__ embed,
    const _Float16* __restrict__ whi, const _Float16* __restrict__ wlo,
    const float* __restrict__ bih,   // wg_bih
    const float* __restrict__ Whh,   // wg_Whh
    const float* __restrict__ bhh,   // wg_bhh
    const float* __restrict__ uaw,   // ua_w
    const float* __restrict__ sWih, const float* __restrict__ sbih,
    const float* __restrict__ sbhh,
    float* __restrict__ gx,          // [NUTT][L][G]
    _Float16* __restrict__ wo16,     // [NUTT][L][D] f16 h history
    int* cnt,                        // 512 flags, 64B-padded: [u][chunk]
    float* __restrict__ out) {       // [NUTT][D]
  __shared__ __align__(16) _Float16 hbuf[2][D];   // f16 h, double-buffered
  __shared__ float pre[3][D];                     // [comp][d] = aR/aZ/aN
  __shared__ float lg[L];
  __shared__ float red[16];
  __shared__ float part[D];
  __shared__ __align__(16) float ut[D];
  // Occupancy limiter: total static LDS > 80 KiB -> 1 block/CU (160 KiB/CU).
  __shared__ __align__(16) char lds_pad[76800];

  const int bx = blockIdx.x;
  const int t = threadIdx.x;
  if (t == 0) ((volatile char*)lds_pad)[0] = 1;   // keep pad live
  const int w = t >> 6;               // wave 0..7
  const int lane = t & 63;
  const int l15 = lane & 15;
  const int lk = lane >> 4;

  if (bx >= NUTT) {
    // ========== gemm producer: one 64-row x 128-col job (R13 math) =======
    const int gbx = bx - NUTT;
    const int rb = gbx / (NUTT * NBLK);        // rowblock-major == chunk-major
    const int rem = gbx % (NUTT * NBLK);
    const int u = rem / NBLK;
    const int nb = rem % NBLK;
    const int m0 = u * L + rb * 64;
    const int wr = w & 3;                      // row-quarter within job
    const int wc = w >> 2;                     // col-half within job
    const int n0 = nb * 128 + wc * 64;
    const int it0 = nb * 8 + wc * 4;

    const int tok = tokens[m0 + 16 * wr + l15];
    const float* arow = embed + (size_t)tok * D;
    const f16x8* Bh = (const f16x8*)whi;
    const f16x8* Bl = (const f16x8*)wlo;
    const int fragbase = lk * 16 + l15;

    f32x4 acc[4] = {};
#pragma unroll
    for (int f = 0; f < 8; ++f) {
      const float* ap = arow + 32 * f + 8 * lk;
      float4 v0 = *(const float4*)(ap);
      float4 v1 = *(const float4*)(ap + 4);
      float av[8] = {v0.x, v0.y, v0.z, v0.w, v1.x, v1.y, v1.z, v1.w};
      f16x8 ahi, alo;
#pragma unroll
      for (int j = 0; j < 8; ++j) {
        _Float16 h = (_Float16)av[j];
        ahi[j] = h;
        alo[j] = (_Float16)(av[j] - (float)h);
      }
#pragma unroll
      for (int i = 0; i < 4; ++i) {
        const int frag = ((it0 + i) * 8 + f) * 64 + fragbase;
        f16x8 bhi = Bh[frag];
        f16x8 blo = Bl[frag];
        acc[i] = __builtin_amdgcn_mfma_f32_16x16x32_f16(ahi, bhi, acc[i], 0, 0, 0);
        acc[i] = __builtin_amdgcn_mfma_f32_16x16x32_f16(alo, bhi, acc[i], 0, 0, 0);
        acc[i] = __builtin_amdgcn_mfma_f32_16x16x32_f16(ahi, blo, acc[i], 0, 0, 0);
      }
    }
#pragma unroll
    for (int i = 0; i < 4; ++i) {
      const int n = n0 + 16 * i + l15;
      const float bb = bih[n];
#pragma unroll
      for (int reg = 0; reg < 4; ++reg) {
        const int m = m0 + 16 * wr + 4 * lk + reg;
        gx[(size_t)m * G + n] = acc[i][reg] + bb;
      }
    }
    __syncthreads();                 // drains all waves' vmcnt
    if (t == 0)
      __hip_atomic_fetch_add(&cnt[((u << 3) + c_chunk_of_rb[rb]) << 4], 1,
                             __ATOMIC_RELEASE, __HIP_MEMORY_SCOPE_AGENT);
    return;
  }

  // ====================== gru consumer role ==============================
  const int b = bx;

  // ---- Bf[i][f][j] = Whh[96w + 16i + l15][32f + 8lk + j], f16 ----
  f16x8 Bf[6][8];
#pragma unroll
  for (int i = 0; i < 6; ++i) {
    const float* row = Whh + (size_t)(96 * w + 16 * i + l15) * D + 8 * lk;
#pragma unroll
    for (int f = 0; f < 8; ++f) {
      float4 v0 = *(const float4*)(row + 32 * f);
      float4 v1 = *(const float4*)(row + 32 * f + 4);
      Bf[i][f] = f16x8{(_Float16)v0.x, (_Float16)v0.y,
                       (_Float16)v0.z, (_Float16)v0.w,
                       (_Float16)v1.x, (_Float16)v1.y,
                       (_Float16)v1.z, (_Float16)v1.w};
    }
  }

  float bR = 0.0f, bZ = 0.0f, bN = 0.0f;
  float gAr = 0.f, gAz = 0.f, gAn = 0.f;   // prefetch triple (even steps)
  float gBr = 0.f, gBz = 0.f, gBn = 0.f;   // prefetch triple (odd steps)
  float hprev = 0.0f;
  float* gxb = gx + (size_t)b * L * G;
  _Float16* wob = wo16 + (size_t)b * L * D;
  if (t < 256) {
    bR = bhh[t]; bZ = bhh[D + t]; bN = bhh[2 * D + t];
    hbuf[0][t] = (_Float16)0.0f;
  }
  __syncthreads();

  const int cstart[5] = {0, 64, 128, 256, 384};
  const int csize[5]  = {64, 64, 128, 128, 128};
  const int cneed[5]  = {6, 6, 12, 12, 12};

  for (int c = 0; c < 5; ++c) {
    // wait for this utterance's chunk c
    if (t == 0) {
      while (__hip_atomic_load(&cnt[((b << 3) + c) << 4],
                               __ATOMIC_ACQUIRE,
                               __HIP_MEMORY_SCOPE_AGENT) < cneed[c])
        __builtin_amdgcn_s_sleep(8);
    }
    __syncthreads();
    __threadfence();
    const int ts0 = cstart[c];
    const int cs = csize[c];
    if (t < 256) {                   // chunk-entry: fill both triples
      const float* g0 = gxb + (size_t)ts0 * G;
      gAr = g0[t]; gAz = g0[D + t]; gAn = g0[2 * D + t];
      const float* g1 = gxb + (size_t)(ts0 + 1) * G;
      gBr = g1[t]; gBz = g1[D + t]; gBn = g1[2 * D + t];
    }

    for (int tsl = 0; tsl < cs; ++tsl) {
      const int ts = ts0 + tsl;
      const int cur = ts & 1;
      const _Float16* hb = hbuf[cur];
      f16x8 A[8];
#pragma unroll
      for (int f = 0; f < 8; ++f)
        A[f] = *(const f16x8*)(hb + 32 * f + 8 * lk);

#pragma unroll
      for (int i = 0; i < 6; ++i) {
        f32x4 acc = {0.0f, 0.0f, 0.0f, 0.0f};
#pragma unroll
        for (int f = 0; f < 8; ++f)
          acc = __builtin_amdgcn_mfma_f32_16x16x32_f16(A[f], Bf[i][f], acc,
                                                       0, 0, 0);
        if (lk == 0) {                // all D rows equal; lanes 0-15 publish
          const int n = 96 * w + 16 * i + l15;
          pre[n >> 8][n & 255] = acc[0];
        }
      }
      lds_barrier();

      if (t < 256) {
        const bool odd = (tsl & 1) != 0;
        float gr = odd ? gBr : gAr;
        float gz = odd ? gBz : gAz;
        float gn = odd ? gBn : gAn;
        float aR = pre[0][t], aZ = pre[1][t], aNp = pre[2][t];
        float r = sigm(gr + aR + bR);
        float z = sigm(gz + aZ + bZ);
        float nn = tanh_f(gn + r * (aNp + bN));
        float hn = fmaf(z, hprev - nn, nn);    // (1-z)*n + z*h
        hprev = hn;
        _Float16 hf = (_Float16)hn;
        hbuf[cur ^ 1][t] = hf;
        wob[(size_t)ts * D + t] = hf;          // f16 history (coalesced)
        if (tsl + 2 < cs) {                    // reload consumed triple, 2 deep
          const float* gxn = gxb + (size_t)(ts + 2) * G;
          if (odd) { gBr = gxn[t]; gBz = gxn[D + t]; gBn = gxn[2 * D + t]; }
          else     { gAr = gxn[t]; gAz = gxn[D + t]; gAn = gxn[2 * D + t]; }
        }
      }
      lds_barrier();
    }
  }

  // ===== fused epilogue: attn-pool (f16 history) + sentence GRU =====
  asm volatile("s_waitcnt vmcnt(0)" ::: "memory");   // wo16 stores done
  __syncthreads();

  // logits: wave w handles rows [64w, 64w+64); f16 rows, 512B each
  {
    const float ua0 = uaw[lane], ua1 = uaw[lane + 64];
    const float ua2 = uaw[lane + 128], ua3 = uaw[lane + 192];
    for (int r = 0; r < 64; ++r) {
      const int tt = 64 * w + r;
      const _Float16* row = wob + (size_t)tt * D;
      float p = (float)row[lane] * ua0 + (float)row[lane + 64] * ua1 +
                (float)row[lane + 128] * ua2 + (float)row[lane + 192] * ua3;
#pragma unroll
      for (int off = 32; off; off >>= 1) p += __shfl_down(p, off);
      if (lane == 0) lg[tt] = p;               // ua_b cancels in softmax
    }
  }
  __syncthreads();

  // softmax over 512 logits (thread t owns lg[t])
  {
    float v = lg[t];
    float m = v;
#pragma unroll
    for (int off = 32; off; off >>= 1) m = fmaxf(m, __shfl_xor(m, off));
    if (lane == 0) red[w] = m;
    __syncthreads();
    m = red[0];
#pragma unroll
    for (int i = 1; i < 8; ++i) m = fmaxf(m, red[i]);
    float e = __expf(v - m);
    float s = e;
#pragma unroll
    for (int off = 32; off; off >>= 1) s += __shfl_xor(s, off);
    if (lane == 0) red[8 + w] = s;
    __syncthreads();
    s = red[8];
#pragma unroll
    for (int i = 9; i < 16; ++i) s += red[i];
    lg[t] = e * (1.0f / s);
  }
  __syncthreads();

  // weighted sum over f16 history: half 0 sums ts in [0,256), half 1 rest
  {
    const int d = t & 255, half = t >> 8;
    float acc = 0.0f;
    const _Float16* bbp = wob + (size_t)half * 256 * D;
    const float* lgh = lg + half * 256;
#pragma unroll 4
    for (int k = 0; k < 256; ++k)
      acc = fmaf(lgh[k], (float)bbp[(size_t)k * D + d], acc);
    if (half == 1) part[d] = acc;
    __syncthreads();
    if (half == 0) ut[d] = acc + part[d];
    __syncthreads();
  }

  // sentence GRU (T=1, h0=0) -> out = (1-z)*n
  if (t < 256) {
    const int d = t;
    const float* wr = sWih + (size_t)d * D;
    const float* wz = sWih + (size_t)(D + d) * D;
    const float* wn = sWih + (size_t)(2 * D + d) * D;
    float ar = 0.0f, az = 0.0f, an = 0.0f;
    for (int k = 0; k < D; k += 4) {
      float4 vr = *(const float4*)(wr + k);
      float4 vz = *(const float4*)(wz + k);
      float4 vn = *(const float4*)(wn + k);
      float u0 = ut[k], u1 = ut[k + 1], u2 = ut[k + 2], u3 = ut[k + 3];
      ar += vr.x * u0 + vr.y * u1 + vr.z * u2 + vr.w * u3;
      az += vz.x * u0 + vz.y * u1 + vz.z * u2 + vz.w * u3;
      an += vn.x * u0 + vn.y * u1 + vn.z * u2 + vn.w * u3;
    }
    float r = sigm(ar + sbih[d] + sbhh[d]);
    float z = sigm(az + sbih[D + d] + sbhh[D + d]);
    float n = tanh_f(an + sbih[2 * D + d] + r * sbhh[2 * D + d]);
    out[(size_t)b * D + d] = (1.0f - z) * n;
  }
}

// ---------------------------------------------------------------------------
extern "C" void kernel_launch(void* const* d_in, const int* in_sizes, int n_in,
                              void* d_out, int out_size, void* d_ws, size_t ws_size,
                              hipStream_t stream) {
  const int* tokens    = (const int*)d_in[0];
  const float* embed   = (const float*)d_in[1];
  const float* wg_Wih  = (const float*)d_in[2];
  const float* wg_Whh  = (const float*)d_in[3];
  const float* wg_bih  = (const float*)d_in[4];
  const float* wg_bhh  = (const float*)d_in[5];
  const float* ua_w    = (const float*)d_in[6];
  // d_in[7] ua_b: softmax shift-invariant -> unused
  const float* sg_Wih  = (const float*)d_in[8];
  // d_in[9] sg_Whh: h0 == 0 -> unused
  const float* sg_bih  = (const float*)d_in[10];
  const float* sg_bhh  = (const float*)d_in[11];
  // d_in[12..13] da_w/da_b: softmax over T=1 -> unused
  float* out = (float*)d_out;

  char* ws = (char*)d_ws;
  const size_t GXB = (size_t)NUTT * L * G * 4;                 // 96 MB
  float* gx = (float*)ws;
  _Float16* whi = (_Float16*)(ws + GXB);                       // 384 KB
  _Float16* wlo = whi + (size_t)G * D;                         // 384 KB
  int* cnt = (int*)(ws + GXB + (size_t)2 * G * D * 2);         // 32 KB flags
  _Float16* wo16 = (_Float16*)(ws + GXB + (size_t)2 * G * D * 2 + 32768);

  pack_wih<<<G, 256, 0, stream>>>(wg_Wih, whi, wlo, cnt);
  hran_mega<<<NUTT + NJOBS, 512, 0, stream>>>(
      tokens, embed, whi, wlo, wg_bih, wg_Whh, wg_bhh, ua_w,
      sg_Wih, sg_bih, sg_bhh, gx, wo16, cnt, out);
}